// Round 2
// baseline (225.664 us; speedup 1.0000x reference)
//
#include <hip/hip_runtime.h>
#include <hip/hip_bf16.h>

// TTT-MLP fused pipeline for MI355X (gfx950), round 2.
//   h    = relu(x @ W1^T + b1)          GEMM1 (fused fp32->bf16 cast of x)
//   pred = h @ W2^T + b2                GEMM2
//   out  = LN(pred @ Wo^T + bo)         GEMM3 fused with LayerNorm
// All LDS tiles use the G4 XOR swizzle via pre-swizzled global source
// (global_load_lds writes linearly; source & read share the involution).

#define HIDDEN 768
#define INNER  512

typedef __bf16 bf16_t;
typedef bf16_t bf16x8 __attribute__((ext_vector_type(8)));
typedef bf16_t bf16x4 __attribute__((ext_vector_type(4)));
typedef float  f32x4  __attribute__((ext_vector_type(4)));

__device__ __forceinline__ void async16(const void* g, void* lds) {
  __builtin_amdgcn_global_load_lds(
      (const __attribute__((address_space(1))) unsigned int*)g,
      (__attribute__((address_space(3))) unsigned int*)lds, 16, 0, 0);
}

// ---------------------------------------------------------------- cast f32->bf16 (weights only)
__global__ __launch_bounds__(256) void cast_bf16(const float4* __restrict__ in,
                                                 bf16x4* __restrict__ out, int n4) {
  int stride = gridDim.x * blockDim.x;
  for (int i = blockIdx.x * blockDim.x + threadIdx.x; i < n4; i += stride) {
    float4 v = in[i];
    bf16x4 o;
    o[0] = (bf16_t)v.x; o[1] = (bf16_t)v.y; o[2] = (bf16_t)v.z; o[3] = (bf16_t)v.w;
    out[i] = o;
  }
}

// ---------------------------------------------------------------- GEMM1: h = relu(x @ W1^T + b1)
// A = x fp32 [M,768] staged as fp32 into LDS (cast at fragment read).
// 128x128 tile, BK=64, 4 waves (2x2), swizzled LDS.
__global__ __launch_bounds__(256)
void gemm1_xcast(const float* __restrict__ x, const bf16_t* __restrict__ W1b,
                 const float* __restrict__ b1, bf16_t* __restrict__ h) {
  __shared__ __align__(16) float  Asf[128 * 64];   // 32 KB fp32
  __shared__ __align__(16) bf16_t Bs[128 * 64];    // 16 KB bf16

  const int per = gridDim.x >> 3;                  // XCD swizzle (grid%8==0)
  const int nb  = (blockIdx.x & 7) * per + (blockIdx.x >> 3);
  const int m0  = (nb >> 2) * 128;                 // NT = 512/128 = 4
  const int n0  = (nb & 3) * 128;

  const int tid = threadIdx.x;
  const int w = tid >> 6, l = tid & 63;
  const int wr = w >> 1, wc = w & 1;
  const int fr = l & 15, fq = l >> 4;

  f32x4 acc[4][4] = {};

  for (int k0 = 0; k0 < HIDDEN; k0 += 64) {
    __syncthreads();
    // A: 128x64 fp32 = 2048 granules(16B), 8 issues/thread, source-swizzled
#pragma unroll
    for (int i = 0; i < 8; ++i) {
      const int G = i * 256 + tid;
      const int row = G >> 4, g = G & 15;
      const int gs = (g & 8) | ((g ^ row) & 7);
      async16(x + (size_t)(m0 + row) * HIDDEN + k0 + gs * 4,
              (char*)Asf + (size_t)(i * 256 + w * 64) * 16);
    }
    // B: 128x64 bf16 = 1024 granules, 4 issues/thread, source-swizzled
#pragma unroll
    for (int i = 0; i < 4; ++i) {
      const int G = i * 256 + tid;
      const int row = G >> 3, g = G & 7;
      async16(W1b + (size_t)(n0 + row) * HIDDEN + k0 + ((g ^ (row & 7)) << 3),
              (char*)Bs + (size_t)(i * 256 + w * 64) * 16);
    }
    __syncthreads();

#pragma unroll
    for (int kk = 0; kk < 2; ++kk) {
      bf16x8 ax[4], bx[4];
#pragma unroll
      for (int m = 0; m < 4; ++m) {
        const int row = wr * 64 + m * 16 + fr;
        const int g0 = kk * 8 + fq * 2;
        const int s0 = (g0 & 8) | ((g0 ^ row) & 7);
        const int s1 = ((g0 + 1) & 8) | (((g0 + 1) ^ row) & 7);
        f32x4 p0 = *(const f32x4*)(Asf + row * 64 + s0 * 4);
        f32x4 p1 = *(const f32x4*)(Asf + row * 64 + s1 * 4);
        bf16x8 a;
#pragma unroll
        for (int c = 0; c < 4; ++c) { a[c] = (bf16_t)p0[c]; a[4 + c] = (bf16_t)p1[c]; }
        ax[m] = a;
      }
#pragma unroll
      for (int n = 0; n < 4; ++n) {
        const int row = wc * 64 + n * 16 + fr;
        const int slot = (kk * 4 + fq) ^ (row & 7);
        bx[n] = *(const bf16x8*)((const char*)Bs + row * 128 + slot * 16);
      }
#pragma unroll
      for (int m = 0; m < 4; ++m)
#pragma unroll
        for (int n = 0; n < 4; ++n)
          acc[m][n] = __builtin_amdgcn_mfma_f32_16x16x32_bf16(ax[m], bx[n], acc[m][n], 0, 0, 0);
    }
  }

  const int orow0 = m0 + wr * 64 + fq * 4;
  const int ocol0 = n0 + wc * 64 + fr;
#pragma unroll
  for (int n = 0; n < 4; ++n) {
    const int col = ocol0 + n * 16;
    const float bv = b1[col];
#pragma unroll
    for (int m = 0; m < 4; ++m)
#pragma unroll
      for (int j = 0; j < 4; ++j) {
        const int row = orow0 + m * 16 + j;
        h[(size_t)row * INNER + col] = (bf16_t)fmaxf(acc[m][n][j] + bv, 0.f);
      }
  }
}

// ---------------------------------------------------------------- GEMM2: pred = h @ W2^T + b2
template <int N_, int K_>
__global__ __launch_bounds__(256)
void gemm_bt(const bf16_t* __restrict__ A, const bf16_t* __restrict__ Bt,
             const float* __restrict__ bias, bf16_t* __restrict__ Cout) {
  constexpr int NT = N_ / 128;
  __shared__ __align__(16) bf16_t As[128 * 64];
  __shared__ __align__(16) bf16_t Bs[128 * 64];

  const int per = gridDim.x >> 3;
  const int nb  = (blockIdx.x & 7) * per + (blockIdx.x >> 3);
  const int m0 = (nb / NT) * 128;
  const int n0 = (nb % NT) * 128;

  const int tid = threadIdx.x;
  const int w = tid >> 6, l = tid & 63;
  const int wr = w >> 1, wc = w & 1;
  const int fr = l & 15, fq = l >> 4;

  f32x4 acc[4][4] = {};

  for (int k0 = 0; k0 < K_; k0 += 64) {
    __syncthreads();
#pragma unroll
    for (int i = 0; i < 4; ++i) {
      const int G = i * 256 + tid;
      const int row = G >> 3, g = G & 7;
      async16(A + (size_t)(m0 + row) * K_ + k0 + ((g ^ (row & 7)) << 3),
              (char*)As + (size_t)(i * 256 + w * 64) * 16);
    }
#pragma unroll
    for (int i = 0; i < 4; ++i) {
      const int G = i * 256 + tid;
      const int row = G >> 3, g = G & 7;
      async16(Bt + (size_t)(n0 + row) * K_ + k0 + ((g ^ (row & 7)) << 3),
              (char*)Bs + (size_t)(i * 256 + w * 64) * 16);
    }
    __syncthreads();

#pragma unroll
    for (int kk = 0; kk < 2; ++kk) {
      bf16x8 ax[4], bx[4];
#pragma unroll
      for (int m = 0; m < 4; ++m) {
        const int row = wr * 64 + m * 16 + fr;
        const int slot = (kk * 4 + fq) ^ (row & 7);
        ax[m] = *(const bf16x8*)((const char*)As + row * 128 + slot * 16);
      }
#pragma unroll
      for (int n = 0; n < 4; ++n) {
        const int row = wc * 64 + n * 16 + fr;
        const int slot = (kk * 4 + fq) ^ (row & 7);
        bx[n] = *(const bf16x8*)((const char*)Bs + row * 128 + slot * 16);
      }
#pragma unroll
      for (int m = 0; m < 4; ++m)
#pragma unroll
        for (int n = 0; n < 4; ++n)
          acc[m][n] = __builtin_amdgcn_mfma_f32_16x16x32_bf16(ax[m], bx[n], acc[m][n], 0, 0, 0);
    }
  }

  const int orow0 = m0 + wr * 64 + fq * 4;
  const int ocol0 = n0 + wc * 64 + fr;
#pragma unroll
  for (int n = 0; n < 4; ++n) {
    const int col = ocol0 + n * 16;
    const float bv = bias[col];
#pragma unroll
    for (int m = 0; m < 4; ++m)
#pragma unroll
      for (int j = 0; j < 4; ++j) {
        const int row = orow0 + m * 16 + j;
        Cout[(size_t)row * N_ + col] = (bf16_t)(acc[m][n][j] + bv);
      }
  }
}

// ---------------------------------------------------------------- GEMM3 + bias + LayerNorm fused
// Block: 64 rows x full 768 cols, 512 threads (8 waves: 4m x 2n).
// pred strip (64x768 bf16, 98 KB) staged once; Wo streamed via 2x16KB dbuf.
// All 96 outputs/lane kept in registers; LN stats via shfl + LDS atomics.
__device__ __forceinline__ void stage_wo(const bf16_t* __restrict__ Wob, int n0p, int k0p,
                                         bf16_t* bufp, int tid, int w) {
#pragma unroll
  for (int i = 0; i < 2; ++i) {
    const int G = i * 512 + tid;               // 1024 granules = 128x64 bf16
    const int row = G >> 3, g = G & 7;
    async16(Wob + (size_t)(n0p + row) * HIDDEN + k0p + ((g ^ (row & 7)) << 3),
            (char*)bufp + (size_t)(i * 512 + (w << 6)) * 16);
  }
}

__global__ __launch_bounds__(512, 2)
void gemm3_ln(const bf16_t* __restrict__ pred, const bf16_t* __restrict__ Wob,
              const float* __restrict__ bo, const float* __restrict__ gamma,
              const float* __restrict__ beta, float* __restrict__ out) {
  __shared__ __align__(16) bf16_t predS[64 * HIDDEN];   // 98304 B (swizzled)
  __shared__ __align__(16) bf16_t Bs[2][128 * 64];      // 32768 B (swizzled, dbuf)
  __shared__ float snorm[2][64];                        // row sums / sumsq -> mu / inv
  __shared__ float bo_s[HIDDEN], ga_s[HIDDEN], be_s[HIDDEN];

  const int tid = threadIdx.x;
  const int w = tid >> 6, l = tid & 63;
  const int wm = w >> 1, wn = w & 1;                    // wave grid 4m x 2n
  const int fr = l & 15, fq = l >> 4;
  const int m0 = blockIdx.x * 64;

  for (int i = tid; i < HIDDEN; i += 512) {
    bo_s[i] = bo[i]; ga_s[i] = gamma[i]; be_s[i] = beta[i];
  }
  if (tid < 64) { snorm[0][tid] = 0.f; snorm[1][tid] = 0.f; }

  // stage pred strip: 6144 granules, 12 issues/thread, source-swizzled
#pragma unroll
  for (int i = 0; i < 12; ++i) {
    const int G = i * 512 + tid;
    const int row = G / 96, g = G % 96;
    const int gs = (g & ~7) | ((g ^ row) & 7);
    async16(pred + (size_t)(m0 + row) * HIDDEN + gs * 8,
            (char*)predS + (size_t)(i * 512 + (w << 6)) * 16);
  }
  stage_wo(Wob, 0, 0, Bs[0], tid, w);   // first K-tile
  __syncthreads();                      // drains all staging

  f32x4 acc[6][4] = {};
  int cur = 0;
#pragma unroll
  for (int nt = 0; nt < 6; ++nt) {
#pragma unroll
    for (int ks = 0; ks < 12; ++ks) {
      if (!(nt == 5 && ks == 11)) {     // prefetch next step into other buffer
        const int pnt = (ks == 11) ? nt + 1 : nt;
        const int pk0 = (ks == 11) ? 0 : (ks + 1) * 64;
        stage_wo(Wob, pnt * 128, pk0, Bs[cur ^ 1], tid, w);
      }
#pragma unroll
      for (int kk = 0; kk < 2; ++kk) {
        const int rowA = wm * 16 + fr;
        const int gA = ks * 8 + kk * 4 + fq;
        const int slotA = (gA & ~7) | ((gA ^ rowA) & 7);
        bf16x8 av = *(const bf16x8*)((const char*)predS + (size_t)rowA * 1536 + slotA * 16);
        bf16x8 bv[4];
#pragma unroll
        for (int n = 0; n < 4; ++n) {
          const int rb = wn * 64 + n * 16 + fr;
          const int slotB = (kk * 4 + fq) ^ (rb & 7);
          bv[n] = *(const bf16x8*)((const char*)Bs[cur] + (size_t)rb * 128 + slotB * 16);
        }
#pragma unroll
        for (int n = 0; n < 4; ++n)
          acc[nt][n] = __builtin_amdgcn_mfma_f32_16x16x32_bf16(av, bv[n], acc[nt][n], 0, 0, 0);
      }
      __syncthreads();
      cur ^= 1;
    }
    // fold bias for this n-tile (needed inside LN stats)
#pragma unroll
    for (int n = 0; n < 4; ++n) {
      const float bvv = bo_s[nt * 128 + wn * 64 + n * 16 + fr];
#pragma unroll
      for (int j = 0; j < 4; ++j) acc[nt][n][j] += bvv;
    }
  }

  // per-row sum / sumsq: reduce over the 16 fr-lanes, atomic into LDS
#pragma unroll
  for (int j = 0; j < 4; ++j) {
    float s = 0.f, q = 0.f;
#pragma unroll
    for (int nt = 0; nt < 6; ++nt)
#pragma unroll
      for (int n = 0; n < 4; ++n) {
        const float v = acc[nt][n][j];
        s += v; q += v * v;
      }
#pragma unroll
    for (int off = 1; off < 16; off <<= 1) {
      s += __shfl_xor(s, off, 64);
      q += __shfl_xor(q, off, 64);
    }
    if (fr == 0) {
      atomicAdd(&snorm[0][wm * 16 + fq * 4 + j], s);
      atomicAdd(&snorm[1][wm * 16 + fq * 4 + j], q);
    }
  }
  __syncthreads();
  if (tid < 64) {
    const float mu  = snorm[0][tid] * (1.f / HIDDEN);
    const float var = fmaxf(snorm[1][tid] * (1.f / HIDDEN) - mu * mu, 0.f);
    snorm[0][tid] = mu;
    snorm[1][tid] = rsqrtf(var + 1e-5f);
  }
  __syncthreads();

  // normalize in-register and store
#pragma unroll
  for (int j = 0; j < 4; ++j) {
    const int r = wm * 16 + fq * 4 + j;
    const float mu = snorm[0][r], inv = snorm[1][r];
    float* orow = out + (size_t)(m0 + r) * HIDDEN;
#pragma unroll
    for (int nt = 0; nt < 6; ++nt)
#pragma unroll
      for (int n = 0; n < 4; ++n) {
        const int col = nt * 128 + wn * 64 + n * 16 + fr;
        orow[col] = (acc[nt][n][j] - mu) * inv * ga_s[col] + be_s[col];
      }
  }
}

// ---------------------------------------------------------------- launch
extern "C" void kernel_launch(void* const* d_in, const int* in_sizes, int n_in,
                              void* d_out, int out_size, void* d_ws, size_t ws_size,
                              hipStream_t stream) {
  const float* x     = (const float*)d_in[0];
  const float* W1    = (const float*)d_in[1];
  const float* b1    = (const float*)d_in[2];
  const float* W2    = (const float*)d_in[3];
  const float* b2    = (const float*)d_in[4];
  const float* Wo    = (const float*)d_in[5];
  const float* bo    = (const float*)d_in[6];
  const float* gamma = (const float*)d_in[7];
  const float* beta  = (const float*)d_in[8];

  const int M = in_sizes[0] / HIDDEN;   // 32768 tokens

  // workspace: h (bf16 M*512) | pred (bf16 M*768) | W1b | W2b | Wob
  char* ws = (char*)d_ws;
  bf16_t* h    = (bf16_t*)ws;
  bf16_t* pred = (bf16_t*)(ws + (size_t)M * INNER * 2);
  bf16_t* W1b  = (bf16_t*)(ws + (size_t)M * INNER * 2 + (size_t)M * HIDDEN * 2);
  bf16_t* W2b  = W1b + INNER * HIDDEN;
  bf16_t* Wob  = W2b + HIDDEN * INNER;

  cast_bf16<<<96,  256, 0, stream>>>((const float4*)W1, (bf16x4*)W1b, INNER * HIDDEN / 4);
  cast_bf16<<<96,  256, 0, stream>>>((const float4*)W2, (bf16x4*)W2b, HIDDEN * INNER / 4);
  cast_bf16<<<144, 256, 0, stream>>>((const float4*)Wo, (bf16x4*)Wob, HIDDEN * HIDDEN / 4);

  gemm1_xcast<<<(M / 128) * (INNER / 128), 256, 0, stream>>>(x, W1b, b1, h);
  gemm_bt<HIDDEN, INNER><<<(M / 128) * (HIDDEN / 128), 256, 0, stream>>>(h, W2b, b2, pred);
  gemm3_ln<<<M / 64, 512, 0, stream>>>(pred, Wob, bo, gamma, beta, (float*)d_out);
}

// Round 3
// 211.080 us; speedup vs baseline: 1.0691x; 1.0691x over previous
//
#include <hip/hip_runtime.h>
#include <hip/hip_bf16.h>

// TTT-MLP pipeline, round 3: 2-phase double-buffered MFMA GEMMs.
//   G1: h    = relu(x @ W1^T + b1)   (x cast fp32->bf16 fused via reg-staging)
//   G2: pred = h @ W2^T + b2
//   G3: out_raw = pred @ Wo^T + bo   (+ per-block LN partial stats to ws)
//   LN: out = (out_raw - mu) * rsqrt(var+eps) * gamma + beta   (in place)
// LDS XOR-swizzle (G4) everywhere; K-loop = T3-minimum 2-phase:
//   prologue STAGE(buf0); barrier; { STAGE(buf^1); COMPUTE(cur); barrier; }

#define HIDDEN 768
#define INNER  512

typedef __bf16 bf16_t;
typedef bf16_t bf16x8 __attribute__((ext_vector_type(8)));
typedef bf16_t bf16x4 __attribute__((ext_vector_type(4)));
typedef float  f32x4  __attribute__((ext_vector_type(4)));

__device__ __forceinline__ void async16(const void* g, void* lds) {
  __builtin_amdgcn_global_load_lds(
      (const __attribute__((address_space(1))) unsigned int*)g,
      (__attribute__((address_space(3))) unsigned int*)lds, 16, 0, 0);
}

// ---------------------------------------------------------------- weight cast
__global__ __launch_bounds__(256) void cast_bf16(const float4* __restrict__ in,
                                                 bf16x4* __restrict__ out, int n4) {
  int stride = gridDim.x * blockDim.x;
  for (int i = blockIdx.x * blockDim.x + threadIdx.x; i < n4; i += stride) {
    float4 v = in[i];
    bf16x4 o;
    o[0] = (bf16_t)v.x; o[1] = (bf16_t)v.y; o[2] = (bf16_t)v.z; o[3] = (bf16_t)v.w;
    out[i] = o;
  }
}

// ---------------------------------------------------------------- G1: h = relu(x@W1^T+b1)
__global__ __launch_bounds__(256, 2)
void gemm1_xcast(const float* __restrict__ x, const bf16_t* __restrict__ W1b,
                 const float* __restrict__ b1, bf16_t* __restrict__ h) {
  __shared__ __align__(16) bf16_t As[2][128 * 64];
  __shared__ __align__(16) bf16_t Bs[2][128 * 64];

  const int per = gridDim.x >> 3;
  const int nb  = (blockIdx.x & 7) * per + (blockIdx.x >> 3);
  const int m0  = (nb >> 2) * 128;             // N=512 -> 4 col-blocks
  const int n0  = (nb & 3) * 128;

  const int tid = threadIdx.x;
  const int w = tid >> 6, l = tid & 63;
  const int wr = w >> 1, wc = w & 1;
  const int fr = l & 15, fq = l >> 4;

  float4 ar[8];                                 // A prefetch regs (fp32)

#define LOAD_A(k0)                                                           \
  _Pragma("unroll") for (int i = 0; i < 8; ++i) {                            \
    const int G = i * 256 + tid, row = G >> 4, g = G & 15;                   \
    ar[i] = *(const float4*)(x + (size_t)(m0 + row) * HIDDEN + (k0) + g * 4);\
  }
#define WRITE_A(buf)                                                         \
  _Pragma("unroll") for (int i = 0; i < 8; ++i) {                            \
    const int G = i * 256 + tid, row = G >> 4, g = G & 15;                   \
    bf16x4 v;                                                                \
    v[0] = (bf16_t)ar[i].x; v[1] = (bf16_t)ar[i].y;                          \
    v[2] = (bf16_t)ar[i].z; v[3] = (bf16_t)ar[i].w;                          \
    *(bf16x4*)((char*)As[buf] + row * 128 +                                  \
               (((g >> 1) ^ (row & 7)) << 4) + ((g & 1) << 3)) = v;          \
  }
#define STAGE_B(buf, k0)                                                     \
  _Pragma("unroll") for (int i = 0; i < 4; ++i) {                            \
    const int G = i * 256 + tid, row = G >> 3, g = G & 7;                    \
    async16(W1b + (size_t)(n0 + row) * HIDDEN + (k0) + ((g ^ (row & 7)) << 3),\
            (char*)Bs[buf] + (size_t)(i * 256 + w * 64) * 16);               \
  }

  LOAD_A(0); STAGE_B(0, 0); WRITE_A(0);
  __syncthreads();

  f32x4 acc[4][4] = {};
#pragma unroll
  for (int t = 0; t < 12; ++t) {
    const int cur = t & 1;
    if (t < 11) { LOAD_A((t + 1) * 64); STAGE_B(cur ^ 1, (t + 1) * 64); }
#pragma unroll
    for (int kk = 0; kk < 2; ++kk) {
      bf16x8 ax[4], bx[4];
#pragma unroll
      for (int m = 0; m < 4; ++m) {
        const int row = wr * 64 + m * 16 + fr;
        const int slot = (kk * 4 + fq) ^ (row & 7);
        ax[m] = *(const bf16x8*)((const char*)As[cur] + row * 128 + slot * 16);
      }
#pragma unroll
      for (int n = 0; n < 4; ++n) {
        const int row = wc * 64 + n * 16 + fr;
        const int slot = (kk * 4 + fq) ^ (row & 7);
        bx[n] = *(const bf16x8*)((const char*)Bs[cur] + row * 128 + slot * 16);
      }
#pragma unroll
      for (int m = 0; m < 4; ++m)
#pragma unroll
        for (int n = 0; n < 4; ++n)
          acc[m][n] = __builtin_amdgcn_mfma_f32_16x16x32_bf16(ax[m], bx[n], acc[m][n], 0, 0, 0);
    }
    if (t < 11) WRITE_A(cur ^ 1);
    __syncthreads();
  }
#undef LOAD_A
#undef WRITE_A
#undef STAGE_B

  const int orow0 = m0 + wr * 64 + fq * 4;
  const int ocol0 = n0 + wc * 64 + fr;
#pragma unroll
  for (int n = 0; n < 4; ++n) {
    const int col = ocol0 + n * 16;
    const float bv = b1[col];
#pragma unroll
    for (int m = 0; m < 4; ++m)
#pragma unroll
      for (int j = 0; j < 4; ++j)
        h[(size_t)(orow0 + m * 16 + j) * INNER + col] = (bf16_t)fmaxf(acc[m][n][j] + bv, 0.f);
  }
}

// ---------------------------------------------------------------- G2/G3 (bf16 A, 2-phase)
// MODE 0: bias -> bf16 (G2).  MODE 1: bias -> fp32 raw + LN partial stats (G3).
template <int N_, int K_, int MODE>
__global__ __launch_bounds__(256, 2)
void gemm_bt(const bf16_t* __restrict__ A, const bf16_t* __restrict__ Bt,
             const float* __restrict__ bias, void* __restrict__ Cout,
             float2* __restrict__ part) {
  constexpr int NT = N_ / 128;
  constexpr int T  = K_ / 64;
  __shared__ __align__(16) bf16_t As[2][128 * 64];
  __shared__ __align__(16) bf16_t Bs[2][128 * 64];

  const int per = gridDim.x >> 3;
  const int nb  = (blockIdx.x & 7) * per + (blockIdx.x >> 3);
  const int m0 = (nb / NT) * 128;
  const int n0 = (nb % NT) * 128;

  const int tid = threadIdx.x;
  const int w = tid >> 6, l = tid & 63;
  const int wr = w >> 1, wc = w & 1;
  const int fr = l & 15, fq = l >> 4;

#define STAGE(dst, src, r0, k0)                                              \
  _Pragma("unroll") for (int i = 0; i < 4; ++i) {                            \
    const int G = i * 256 + tid, row = G >> 3, g = G & 7;                    \
    async16((src) + (size_t)((r0) + row) * K_ + (k0) + ((g ^ (row & 7)) << 3),\
            (char*)(dst) + (size_t)(i * 256 + w * 64) * 16);                 \
  }

  STAGE(As[0], A, m0, 0); STAGE(Bs[0], Bt, n0, 0);
  __syncthreads();

  f32x4 acc[4][4] = {};
#pragma unroll
  for (int t = 0; t < T; ++t) {
    const int cur = t & 1;
    if (t < T - 1) {
      STAGE(As[cur ^ 1], A, m0, (t + 1) * 64);
      STAGE(Bs[cur ^ 1], Bt, n0, (t + 1) * 64);
    }
#pragma unroll
    for (int kk = 0; kk < 2; ++kk) {
      bf16x8 ax[4], bx[4];
#pragma unroll
      for (int m = 0; m < 4; ++m) {
        const int row = wr * 64 + m * 16 + fr;
        const int slot = (kk * 4 + fq) ^ (row & 7);
        ax[m] = *(const bf16x8*)((const char*)As[cur] + row * 128 + slot * 16);
      }
#pragma unroll
      for (int n = 0; n < 4; ++n) {
        const int row = wc * 64 + n * 16 + fr;
        const int slot = (kk * 4 + fq) ^ (row & 7);
        bx[n] = *(const bf16x8*)((const char*)Bs[cur] + row * 128 + slot * 16);
      }
#pragma unroll
      for (int m = 0; m < 4; ++m)
#pragma unroll
        for (int n = 0; n < 4; ++n)
          acc[m][n] = __builtin_amdgcn_mfma_f32_16x16x32_bf16(ax[m], bx[n], acc[m][n], 0, 0, 0);
    }
    __syncthreads();
  }
#undef STAGE

  const int orow0 = m0 + wr * 64 + fq * 4;
  const int ocol0 = n0 + wc * 64 + fr;

  // fold bias into acc
#pragma unroll
  for (int n = 0; n < 4; ++n) {
    const float bv = bias[ocol0 + n * 16];
#pragma unroll
    for (int m = 0; m < 4; ++m)
#pragma unroll
      for (int j = 0; j < 4; ++j) acc[m][n][j] += bv;
  }

  if (MODE == 1) {
    // per-row partial sum/sumsq over this block's 64 wave-cols, fr-lane reduce
    const int nb2 = (n0 >> 7) * 2 + wc;
#pragma unroll
    for (int m = 0; m < 4; ++m)
#pragma unroll
      for (int j = 0; j < 4; ++j) {
        float s = 0.f, q = 0.f;
#pragma unroll
        for (int n = 0; n < 4; ++n) { const float v = acc[m][n][j]; s += v; q += v * v; }
#pragma unroll
        for (int off = 1; off < 16; off <<= 1) {
          s += __shfl_xor(s, off, 64);
          q += __shfl_xor(q, off, 64);
        }
        if (fr == 0)
          part[(size_t)(orow0 + m * 16 + j) * (2 * NT) + nb2] = make_float2(s, q);
      }
  }

#pragma unroll
  for (int n = 0; n < 4; ++n) {
    const int col = ocol0 + n * 16;
#pragma unroll
    for (int m = 0; m < 4; ++m)
#pragma unroll
      for (int j = 0; j < 4; ++j) {
        const int row = orow0 + m * 16 + j;
        if (MODE == 1) ((float*)Cout)[(size_t)row * N_ + col] = acc[m][n][j];
        else           ((bf16_t*)Cout)[(size_t)row * N_ + col] = (bf16_t)acc[m][n][j];
      }
  }
}

// ---------------------------------------------------------------- LN apply (in place)
__global__ __launch_bounds__(256)
void ln_apply(float* __restrict__ io, const float2* __restrict__ part,
              const float* __restrict__ gamma, const float* __restrict__ beta, int rows) {
  const int l = threadIdx.x & 63;
  for (int r = blockIdx.x * 4 + (threadIdx.x >> 6); r < rows; r += gridDim.x * 4) {
    float s = 0.f, q = 0.f;
#pragma unroll
    for (int i = 0; i < 12; ++i) { const float2 p = part[(size_t)r * 12 + i]; s += p.x; q += p.y; }
    const float mu  = s * (1.0f / HIDDEN);
    const float var = fmaxf(q * (1.0f / HIDDEN) - mu * mu, 0.f);
    const float inv = rsqrtf(var + 1e-5f);
    float* rp = io + (size_t)r * HIDDEN;
#pragma unroll
    for (int i = 0; i < 3; ++i) {
      float4 v = ((const float4*)rp)[i * 64 + l];
      float4 g = ((const float4*)gamma)[i * 64 + l];
      float4 b = ((const float4*)beta)[i * 64 + l];
      float4 o;
      o.x = (v.x - mu) * inv * g.x + b.x;
      o.y = (v.y - mu) * inv * g.y + b.y;
      o.z = (v.z - mu) * inv * g.z + b.z;
      o.w = (v.w - mu) * inv * g.w + b.w;
      ((float4*)rp)[i * 64 + l] = o;
    }
  }
}

// ---------------------------------------------------------------- launch
extern "C" void kernel_launch(void* const* d_in, const int* in_sizes, int n_in,
                              void* d_out, int out_size, void* d_ws, size_t ws_size,
                              hipStream_t stream) {
  const float* x     = (const float*)d_in[0];
  const float* W1    = (const float*)d_in[1];
  const float* b1    = (const float*)d_in[2];
  const float* W2    = (const float*)d_in[3];
  const float* b2    = (const float*)d_in[4];
  const float* Wo    = (const float*)d_in[5];
  const float* bo    = (const float*)d_in[6];
  const float* gamma = (const float*)d_in[7];
  const float* beta  = (const float*)d_in[8];

  const int M = in_sizes[0] / HIDDEN;   // 32768 tokens

  // ws: h (M*512 bf16) | pred (M*768 bf16) | W1b | W2b | Wob
  // part (LN stats, M*12 float2 = 3.1 MB) overlays h (dead after G2).
  char* ws = (char*)d_ws;
  bf16_t* h    = (bf16_t*)ws;
  float2* part = (float2*)ws;
  bf16_t* pred = (bf16_t*)(ws + (size_t)M * INNER * 2);
  bf16_t* W1b  = (bf16_t*)(ws + (size_t)M * INNER * 2 + (size_t)M * HIDDEN * 2);
  bf16_t* W2b  = W1b + INNER * HIDDEN;
  bf16_t* Wob  = W2b + HIDDEN * INNER;

  cast_bf16<<<96,  256, 0, stream>>>((const float4*)W1, (bf16x4*)W1b, INNER * HIDDEN / 4);
  cast_bf16<<<96,  256, 0, stream>>>((const float4*)W2, (bf16x4*)W2b, HIDDEN * INNER / 4);
  cast_bf16<<<144, 256, 0, stream>>>((const float4*)Wo, (bf16x4*)W2b == nullptr ? nullptr : (bf16x4*)Wob, HIDDEN * HIDDEN / 4);

  gemm1_xcast<<<(M / 128) * (INNER / 128), 256, 0, stream>>>(x, W1b, b1, h);
  gemm_bt<HIDDEN, INNER,  0><<<(M / 128) * (HIDDEN / 128), 256, 0, stream>>>(h,    W2b, b2, pred, nullptr);
  gemm_bt<HIDDEN, HIDDEN, 1><<<(M / 128) * (HIDDEN / 128), 256, 0, stream>>>(pred, Wob, bo, d_out, part);
  ln_apply<<<2048, 256, 0, stream>>>((float*)d_out, part, gamma, beta, M);
}

// Round 4
// 140.455 us; speedup vs baseline: 1.6067x; 1.5028x over previous
//
#include <hip/hip_runtime.h>
#include <hip/hip_bf16.h>

// TTT-MLP, round 4. Algebraic fusion: the TTT inner loop never updates the
// weights, so  out = LN( h @ (Wo@W2)^T + (Wo@b2+bo) ),  h = relu(x@W1^T+b1).
// Pipeline: prep(cast x/W1/Wo, cast+transpose W2) -> beq -> Gw(Weq, tiny)
//           -> G1 -> G2'(bf16 raw out) -> LN (stats in-wave, fp32 out).
// GEMMs: proven round-3 2-phase dbuf structure, XOR-swizzled LDS, async16.

#define HIDDEN 768
#define INNER  512

typedef __bf16 bf16_t;
typedef bf16_t bf16x8 __attribute__((ext_vector_type(8)));
typedef bf16_t bf16x4 __attribute__((ext_vector_type(4)));
typedef float  f32x4  __attribute__((ext_vector_type(4)));

__device__ __forceinline__ void async16(const void* g, void* lds) {
  __builtin_amdgcn_global_load_lds(
      (const __attribute__((address_space(1))) unsigned int*)g,
      (__attribute__((address_space(3))) unsigned int*)lds, 16, 0, 0);
}

// ---------------------------------------------------------------- prep: casts + W2 transpose
// blocks [0,xb_b): x->xb ; [xb_b,+24): W1 ; [+24,+36): Wo ; last 96: W2->W2t (transposed)
__global__ __launch_bounds__(256)
void prep(const float* __restrict__ x, const float* __restrict__ W1,
          const float* __restrict__ W2, const float* __restrict__ Wo,
          bf16_t* __restrict__ xb, bf16_t* __restrict__ W1b,
          bf16_t* __restrict__ W2t, bf16_t* __restrict__ Wob, int xb_blocks) {
  __shared__ float T[64][65];
  const int b = blockIdx.x, t = threadIdx.x;

  const float4* src; bf16x4* dst; int base;
  if (b < xb_blocks)            { src = (const float4*)x;  dst = (bf16x4*)xb;  base = b * 4096; }
  else if (b < xb_blocks + 24)  { src = (const float4*)W1; dst = (bf16x4*)W1b; base = (b - xb_blocks) * 4096; }
  else if (b < xb_blocks + 60)  { src = (const float4*)Wo; dst = (bf16x4*)Wob; base = (b - xb_blocks - 24) * 4096; }
  else {
    // W2 [768,512] -> W2t [512,768], 64x64 tile per block (96 tiles)
    const int tile = b - xb_blocks - 60;
    const int d0 = (tile >> 3) << 6;   // 12 d-tiles
    const int i0 = (tile & 7) << 6;    // 8  i-tiles
#pragma unroll
    for (int j = 0; j < 4; ++j) {
      const int idx = j * 256 + t;     // 1024 float4 = 64x64 f32
      const int r = idx >> 4, c4 = idx & 15;
      float4 v = *(const float4*)(W2 + (size_t)(d0 + r) * INNER + i0 + c4 * 4);
      T[r][c4 * 4 + 0] = v.x; T[r][c4 * 4 + 1] = v.y;
      T[r][c4 * 4 + 2] = v.z; T[r][c4 * 4 + 3] = v.w;
    }
    __syncthreads();
    const int i = t & 63, h4 = t >> 6;           // 4 col-chunks of 16
    bf16x8 o0, o1;
#pragma unroll
    for (int c = 0; c < 8; ++c) { o0[c] = (bf16_t)T[h4 * 16 + c][i]; o1[c] = (bf16_t)T[h4 * 16 + 8 + c][i]; }
    bf16_t* orow = W2t + (size_t)(i0 + i) * HIDDEN + d0 + h4 * 16;
    *(bf16x8*)orow = o0;
    *(bf16x8*)(orow + 8) = o1;
    return;
  }
#pragma unroll
  for (int i = 0; i < 16; ++i) {
    float4 v = src[base + i * 256 + t];
    bf16x4 o;
    o[0] = (bf16_t)v.x; o[1] = (bf16_t)v.y; o[2] = (bf16_t)v.z; o[3] = (bf16_t)v.w;
    dst[base + i * 256 + t] = o;
  }
}

// ---------------------------------------------------------------- beq = Wo @ b2 + bo (wave/row)
__global__ __launch_bounds__(256)
void beq_k(const float* __restrict__ Wo, const float* __restrict__ b2,
           const float* __restrict__ bo, float* __restrict__ beq) {
  const int e = blockIdx.x * 4 + (threadIdx.x >> 6);
  const int l = threadIdx.x & 63;
  float s = 0.f;
#pragma unroll
  for (int j = 0; j < 12; ++j) s += Wo[(size_t)e * HIDDEN + j * 64 + l] * b2[j * 64 + l];
#pragma unroll
  for (int off = 1; off < 64; off <<= 1) s += __shfl_xor(s, off, 64);
  if (l == 0) beq[e] = s + bo[e];
}

// ---------------------------------------------------------------- GEMM (A[M,K] x Bt[N,K]) -> bf16
// MODE 0: bias+relu ; MODE 1: bias ; MODE 2: plain. 2-phase dbuf, swizzled.
template <int N_, int K_, int MODE>
__global__ __launch_bounds__(256, 2)
void gemm_bt(const bf16_t* __restrict__ A, const bf16_t* __restrict__ Bt,
             const float* __restrict__ bias, bf16_t* __restrict__ Cout) {
  constexpr int NT = N_ / 128;
  constexpr int T  = K_ / 64;
  __shared__ __align__(16) bf16_t As[2][128 * 64];
  __shared__ __align__(16) bf16_t Bs[2][128 * 64];

  const int per = gridDim.x >> 3;
  const int nb  = (blockIdx.x & 7) * per + (blockIdx.x >> 3);
  const int m0 = (nb / NT) * 128;
  const int n0 = (nb % NT) * 128;

  const int tid = threadIdx.x;
  const int w = tid >> 6, l = tid & 63;
  const int wr = w >> 1, wc = w & 1;
  const int fr = l & 15, fq = l >> 4;

#define STAGE(dst, src, r0, k0)                                               \
  _Pragma("unroll") for (int i = 0; i < 4; ++i) {                             \
    const int G = i * 256 + tid, row = G >> 3, g = G & 7;                     \
    async16((src) + (size_t)((r0) + row) * K_ + (k0) + ((g ^ (row & 7)) << 3),\
            (char*)(dst) + (size_t)(i * 256 + w * 64) * 16);                  \
  }

  STAGE(As[0], A, m0, 0); STAGE(Bs[0], Bt, n0, 0);
  __syncthreads();

  f32x4 acc[4][4] = {};
#pragma unroll
  for (int t = 0; t < T; ++t) {
    const int cur = t & 1;
    if (t < T - 1) {
      STAGE(As[cur ^ 1], A, m0, (t + 1) * 64);
      STAGE(Bs[cur ^ 1], Bt, n0, (t + 1) * 64);
    }
#pragma unroll
    for (int kk = 0; kk < 2; ++kk) {
      bf16x8 ax[4], bx[4];
#pragma unroll
      for (int m = 0; m < 4; ++m) {
        const int row = wr * 64 + m * 16 + fr;
        const int slot = (kk * 4 + fq) ^ (row & 7);
        ax[m] = *(const bf16x8*)((const char*)As[cur] + row * 128 + slot * 16);
      }
#pragma unroll
      for (int n = 0; n < 4; ++n) {
        const int row = wc * 64 + n * 16 + fr;
        const int slot = (kk * 4 + fq) ^ (row & 7);
        bx[n] = *(const bf16x8*)((const char*)Bs[cur] + row * 128 + slot * 16);
      }
#pragma unroll
      for (int m = 0; m < 4; ++m)
#pragma unroll
        for (int n = 0; n < 4; ++n)
          acc[m][n] = __builtin_amdgcn_mfma_f32_16x16x32_bf16(ax[m], bx[n], acc[m][n], 0, 0, 0);
    }
    __syncthreads();
  }
#undef STAGE

  const int orow0 = m0 + wr * 64 + fq * 4;
  const int ocol0 = n0 + wc * 64 + fr;
#pragma unroll
  for (int n = 0; n < 4; ++n) {
    const int col = ocol0 + n * 16;
    const float bv = (MODE == 2) ? 0.f : bias[col];
#pragma unroll
    for (int m = 0; m < 4; ++m)
#pragma unroll
      for (int j = 0; j < 4; ++j) {
        float v = acc[m][n][j] + bv;
        if (MODE == 0) v = fmaxf(v, 0.f);
        Cout[(size_t)(orow0 + m * 16 + j) * N_ + col] = (bf16_t)v;
      }
  }
}

// ---------------------------------------------------------------- LN: bf16 raw -> fp32 out (wave/row)
__global__ __launch_bounds__(256)
void ln_bf16(const bf16_t* __restrict__ raw, const float* __restrict__ gamma,
             const float* __restrict__ beta, float* __restrict__ out) {
  const int r = blockIdx.x * 4 + (threadIdx.x >> 6);
  const int l = threadIdx.x & 63;
  const bf16_t* rp = raw + (size_t)r * HIDDEN;
  float v[12];
  float s = 0.f, q = 0.f;
#pragma unroll
  for (int c = 0; c < 3; ++c) {
    bf16x4 b4 = *(const bf16x4*)(rp + c * 256 + l * 4);
#pragma unroll
    for (int j = 0; j < 4; ++j) {
      const float f = (float)b4[j];
      v[c * 4 + j] = f; s += f; q += f * f;
    }
  }
#pragma unroll
  for (int off = 1; off < 64; off <<= 1) {
    s += __shfl_xor(s, off, 64);
    q += __shfl_xor(q, off, 64);
  }
  const float mu  = s * (1.0f / HIDDEN);
  const float var = fmaxf(q * (1.0f / HIDDEN) - mu * mu, 0.f);
  const float inv = rsqrtf(var + 1e-5f);
  float* op = out + (size_t)r * HIDDEN;
#pragma unroll
  for (int c = 0; c < 3; ++c) {
    float4 g = ((const float4*)gamma)[c * 64 + l];
    float4 b = ((const float4*)beta)[c * 64 + l];
    float4 o;
    o.x = (v[c * 4 + 0] - mu) * inv * g.x + b.x;
    o.y = (v[c * 4 + 1] - mu) * inv * g.y + b.y;
    o.z = (v[c * 4 + 2] - mu) * inv * g.z + b.z;
    o.w = (v[c * 4 + 3] - mu) * inv * g.w + b.w;
    ((float4*)op)[c * 64 + l] = o;
  }
}

// ---------------------------------------------------------------- launch
extern "C" void kernel_launch(void* const* d_in, const int* in_sizes, int n_in,
                              void* d_out, int out_size, void* d_ws, size_t ws_size,
                              hipStream_t stream) {
  const float* x     = (const float*)d_in[0];
  const float* W1    = (const float*)d_in[1];
  const float* b1    = (const float*)d_in[2];
  const float* W2    = (const float*)d_in[3];
  const float* b2    = (const float*)d_in[4];
  const float* Wo    = (const float*)d_in[5];
  const float* bo    = (const float*)d_in[6];
  const float* gamma = (const float*)d_in[7];
  const float* beta  = (const float*)d_in[8];

  const int M = in_sizes[0] / HIDDEN;   // 32768 tokens

  // ws layout:
  //   region0: xb (bf16 M*768) -- dead after G1, reused as raw out (bf16 M*768)
  //   region1: h  (bf16 M*512)
  //   region2: W1b | W2t | Wob | Weq | beq
  char* ws = (char*)d_ws;
  bf16_t* xb   = (bf16_t*)ws;
  bf16_t* raw  = xb;                                     // overlay (xb dead after G1)
  bf16_t* h    = (bf16_t*)(ws + (size_t)M * HIDDEN * 2);
  bf16_t* W1b  = (bf16_t*)(ws + (size_t)M * HIDDEN * 2 + (size_t)M * INNER * 2);
  bf16_t* W2t  = W1b + INNER * HIDDEN;                   // [512,768] transposed
  bf16_t* Wob  = W2t + INNER * HIDDEN;                   // [768,768]
  bf16_t* Weq  = Wob + HIDDEN * HIDDEN;                  // [768,512]
  float*  beq  = (float*)(Weq + HIDDEN * INNER);

  const int xb_blocks = (M * HIDDEN / 4) / 4096;         // 1536 for M=32768

  prep<<<xb_blocks + 60 + 96, 256, 0, stream>>>(x, W1, W2, Wo, xb, W1b, W2t, Wob, xb_blocks);
  beq_k<<<HIDDEN / 4, 256, 0, stream>>>(Wo, b2, bo, beq);

  // Weq = Wo @ W2  ->  gemm_bt(A=Wob [768,768], Bt=W2t [512,768]) -> [768,512]
  gemm_bt<INNER, HIDDEN, 2><<<(HIDDEN / 128) * (INNER / 128), 256, 0, stream>>>(Wob, W2t, nullptr, Weq);
  // h = relu(xb @ W1^T + b1)
  gemm_bt<INNER, HIDDEN, 0><<<(M / 128) * (INNER / 128), 256, 0, stream>>>(xb, W1b, b1, h);
  // raw = h @ Weq^T + beq   (bf16)
  gemm_bt<HIDDEN, INNER, 1><<<(M / 128) * (HIDDEN / 128), 256, 0, stream>>>(h, Weq, beq, raw);
  // out = LN(raw) * gamma + beta  (fp32)
  ln_bf16<<<M / 4, 256, 0, stream>>>(raw, gamma, beta, (float*)d_out);
}